// Round 1
// baseline (206.309 us; speedup 1.0000x reference)
//
#include <hip/hip_runtime.h>
#include <math.h>

#define RESG 128
#define CHG 28
#define NSAMP 768
#define NT 767          // N_SAMPLES - 1

__global__ __launch_bounds__(256) void nerf_grid_kernel(
    const float* __restrict__ rays_d,
    const float* __restrict__ rays_o,
    const float* __restrict__ grid,     // [128^3][28] f32
    float* __restrict__ out_rgb,        // [B][3]
    float* __restrict__ out_alpha,      // [B][767]
    float* __restrict__ out_depth)      // [B]
{
    const int ray  = blockIdx.x;
    const int tid  = threadIdx.x;
    const int lane = tid & 63;
    const int wave = tid >> 6;

    const float STEPC = 2.0f / 127.0f;
    const float EPSC  = 1e-10f;

    // ---- per-ray setup (redundant per thread; trivial cost) ----
    const float ox = rays_o[ray*3+0], oy = rays_o[ray*3+1], oz = rays_o[ray*3+2];
    const float dx = rays_d[ray*3+0], dy = rays_d[ray*3+1], dz = rays_d[ray*3+2];
    const float dnorm = sqrtf(dx*dx + dy*dy + dz*dz);

    // slab intersection with [-1,1]^3
    float txp = (1.0f - ox)/dx, txn = (-1.0f - ox)/dx;
    float typ = (1.0f - oy)/dy, tyn = (-1.0f - oy)/dy;
    float tzp = (1.0f - oz)/dz, tzn = (-1.0f - oz)/dz;
    float start = fmaxf(fmaxf(fminf(txp,txn), fminf(typ,tyn)), fminf(tzp,tzn));
    float stop  = fminf(fminf(fmaxf(txp,txn), fmaxf(typ,tyn)), fmaxf(tzp,tzn));

    const float s0 = start + 0.5f*STEPC;
    const float s1 = start + 0.5f*STEPC*(float)NSAMP;

    // SH deg-2 basis from normalized direction
    const float inv = 1.0f/dnorm;
    const float nx = dx*inv, ny = dy*inv, nz = dz*inv;
    float sh[9];
    {
        const float C0 = 0.28209479177387814f;
        const float C1 = 0.4886025119029199f;
        const float C20 = 1.0925484305920792f, C21 = -1.0925484305920792f;
        const float C22 = 0.31539156525252005f;
        const float C23 = -1.0925484305920792f, C24 = 0.5462742152960396f;
        sh[0] = C0;
        sh[1] = -C1*ny;
        sh[2] =  C1*nz;
        sh[3] = -C1*nx;
        sh[4] = C20*nx*ny;
        sh[5] = C21*ny*nz;
        sh[6] = C22*(2.0f*nz*nz - nx*nx - ny*ny);
        sh[7] = C23*nx*nz;
        sh[8] = C24*(nx*nx - ny*ny);
    }

    // ---- phase 1: per-sample alpha / sigmoid(rgb) / t ----
    float a_r[3], q_r[3], t_r[3], rr_r[3], gg_r[3], bb_r[3];

    #pragma unroll
    for (int k = 0; k < 3; ++k) {
        const int s = tid*3 + k;
        float a = 0.0f, rr = 0.0f, gg = 0.0f, bb = 0.0f, tt = 0.0f, q = 1.0f;
        if (s < NT) {
            const float w0 = (float)s     * (1.0f/767.0f);
            const float w1 = (float)(s+1) * (1.0f/767.0f);
            const float t0 = fminf(s0*(1.0f-w0) + s1*w0, stop);
            const float t1 = fminf(s0*(1.0f-w1) + s1*w1, stop);
            const float dist = (t1 - t0) * dnorm;
            tt = t0;
            if (dist > 0.0f) {
                // sample position; AABB=[-1,1] so normalized coords == pts
                const float px = ox + t0*dx, py = oy + t0*dy, pz = oz + t0*dz;
                const float gx = (px + 1.0f)*63.5f;
                const float gy = (py + 1.0f)*63.5f;
                const float gz = (pz + 1.0f)*63.5f;
                const float fx0 = floorf(gx), fy0 = floorf(gy), fz0 = floorf(gz);
                const float fx = gx - fx0, fy = gy - fy0, fz = gz - fz0;
                const int ix = (int)fx0, iy = (int)fy0, iz = (int)fz0;

                float acc[CHG];
                #pragma unroll
                for (int c = 0; c < CHG; ++c) acc[c] = 0.0f;

                #pragma unroll
                for (int dzz = 0; dzz < 2; ++dzz)
                #pragma unroll
                for (int dyy = 0; dyy < 2; ++dyy)
                #pragma unroll
                for (int dxx = 0; dxx < 2; ++dxx) {
                    const int xi = ix + dxx, yi = iy + dyy, zi = iz + dzz;
                    const bool valid = (xi >= 0) & (xi < RESG) &
                                       (yi >= 0) & (yi < RESG) &
                                       (zi >= 0) & (zi < RESG);
                    const float wgt = (dxx ? fx : 1.0f-fx) *
                                      (dyy ? fy : 1.0f-fy) *
                                      (dzz ? fz : 1.0f-fz);
                    if (valid && wgt != 0.0f) {
                        const size_t idx = ((size_t)zi*RESG + yi)*RESG + xi;
                        const float4* row = (const float4*)(grid + idx*CHG);
                        #pragma unroll
                        for (int c4 = 0; c4 < 7; ++c4) {
                            const float4 v = row[c4];
                            acc[c4*4+0] += wgt*v.x;
                            acc[c4*4+1] += wgt*v.y;
                            acc[c4*4+2] += wgt*v.z;
                            acc[c4*4+3] += wgt*v.w;
                        }
                    }
                }

                const float sigma = acc[27];
                float r = 0.0f, g = 0.0f, b = 0.0f;
                #pragma unroll
                for (int j = 0; j < 9; ++j) {
                    r += acc[j]      * sh[j];
                    g += acc[9+j]    * sh[j];
                    b += acc[18+j]   * sh[j];
                }
                a  = 1.0f - expf(-fmaxf(sigma, 0.0f)*dist);
                rr = 1.0f/(1.0f + expf(-r));
                gg = 1.0f/(1.0f + expf(-g));
                bb = 1.0f/(1.0f + expf(-b));
            }
            q = 1.0f - a + EPSC;
            out_alpha[(size_t)ray*NT + s] = a;
        }
        a_r[k] = a; q_r[k] = q; t_r[k] = tt;
        rr_r[k] = rr; gg_r[k] = gg; bb_r[k] = bb;
    }

    // ---- phase 2: block-wide exclusive product scan over q ----
    const float P = q_r[0]*q_r[1]*q_r[2];
    float incl = P;
    #pragma unroll
    for (int off = 1; off < 64; off <<= 1) {
        const float n = __shfl_up(incl, off, 64);
        if (lane >= off) incl *= n;
    }
    float excl = __shfl_up(incl, 1, 64);
    if (lane == 0) excl = 1.0f;

    __shared__ float wprod[4];
    __shared__ float red[4][5];
    if (lane == 63) wprod[wave] = incl;
    __syncthreads();
    float wpre = 1.0f;
    for (int w2 = 0; w2 < 4; ++w2) if (w2 < wave) wpre *= wprod[w2];

    // ---- phase 3: weighted accumulation ----
    float cum = wpre * excl;
    float accA = 0.0f, accR = 0.0f, accG = 0.0f, accB = 0.0f, accD = 0.0f;
    #pragma unroll
    for (int k = 0; k < 3; ++k) {
        const float abs_l = a_r[k] * cum;
        accA += abs_l;
        accR += abs_l * rr_r[k];
        accG += abs_l * gg_r[k];
        accB += abs_l * bb_r[k];
        accD += abs_l * t_r[k];
        cum *= q_r[k];
    }

    // wave reduce (64 lanes)
    #pragma unroll
    for (int off = 32; off > 0; off >>= 1) {
        accA += __shfl_down(accA, off, 64);
        accR += __shfl_down(accR, off, 64);
        accG += __shfl_down(accG, off, 64);
        accB += __shfl_down(accB, off, 64);
        accD += __shfl_down(accD, off, 64);
    }
    if (lane == 0) {
        red[wave][0] = accA; red[wave][1] = accR; red[wave][2] = accG;
        red[wave][3] = accB; red[wave][4] = accD;
    }
    __syncthreads();
    if (tid == 0) {
        float A = 0.0f, R = 0.0f, G = 0.0f, Bv = 0.0f, D = 0.0f;
        #pragma unroll
        for (int w2 = 0; w2 < 4; ++w2) {
            A += red[w2][0]; R += red[w2][1]; G += red[w2][2];
            Bv += red[w2][3]; D += red[w2][4];
        }
        const float bg = 1.0f - A;
        out_rgb[ray*3+0] = R  + bg;
        out_rgb[ray*3+1] = G  + bg;
        out_rgb[ray*3+2] = Bv + bg;
        out_depth[ray] = D;
    }
}

extern "C" void kernel_launch(void* const* d_in, const int* in_sizes, int n_in,
                              void* d_out, int out_size, void* d_ws, size_t ws_size,
                              hipStream_t stream) {
    const float* rays_d = (const float*)d_in[0];
    const float* rays_o = (const float*)d_in[1];
    const float* grid   = (const float*)d_in[2];
    const int B = in_sizes[0] / 3;   // 4096

    float* out       = (float*)d_out;
    float* out_rgb   = out;                                  // B*3
    float* out_alpha = out + (size_t)B*3;                    // B*767
    float* out_depth = out + (size_t)B*3 + (size_t)B*NT;     // B

    nerf_grid_kernel<<<B, 256, 0, stream>>>(rays_d, rays_o, grid,
                                            out_rgb, out_alpha, out_depth);
}

// Round 2
// 85.962 us; speedup vs baseline: 2.4000x; 2.4000x over previous
//
#include <hip/hip_runtime.h>
#include <math.h>

#define RESG 128
#define CHG 28
#define NT 767          // N_SAMPLES - 1

__global__ __launch_bounds__(256) void nerf_grid_kernel(
    const float* __restrict__ rays_d,
    const float* __restrict__ rays_o,
    const float* __restrict__ grid,     // [128^3][28] f32
    float* __restrict__ out_rgb,        // [B][3]
    float* __restrict__ out_alpha,      // [B][767]
    float* __restrict__ out_depth)      // [B]
{
    const int ray  = blockIdx.x;
    const int tid  = threadIdx.x;
    const int lane = tid & 63;
    const int wave = tid >> 6;

    const float EPSC   = 1e-10f;
    const float INV127 = 1.0f / 127.0f;   // 0.5 * STEP

    __shared__ float a_lds[NT + 1];
    __shared__ float r_lds[NT + 1];
    __shared__ float g_lds[NT + 1];
    __shared__ float b_lds[NT + 1];
    __shared__ float wprod[4];
    __shared__ float red[4][5];

    // ---- per-ray setup (redundant per thread) ----
    const float ox = rays_o[ray*3+0], oy = rays_o[ray*3+1], oz = rays_o[ray*3+2];
    const float dx = rays_d[ray*3+0], dy = rays_d[ray*3+1], dz = rays_d[ray*3+2];
    const float dnorm = sqrtf(dx*dx + dy*dy + dz*dz);

    float txp = (1.0f - ox)/dx, txn = (-1.0f - ox)/dx;
    float typ = (1.0f - oy)/dy, tyn = (-1.0f - oy)/dy;
    float tzp = (1.0f - oz)/dz, tzn = (-1.0f - oz)/dz;
    const float start = fmaxf(fmaxf(fminf(txp,txn), fminf(typ,tyn)), fminf(tzp,tzn));
    const float stop  = fminf(fminf(fmaxf(txp,txn), fmaxf(typ,tyn)), fmaxf(tzp,tzn));

    // conservative live-sample count: for s >= n_proc, t0(s) >= stop -> dist == 0
    int n_proc = (int)((stop - start) * 127.0f) + 2;
    n_proc = n_proc < 0 ? 0 : (n_proc > NT ? NT : n_proc);

    // SH deg-2 basis
    const float inv = 1.0f/dnorm;
    const float nx = dx*inv, ny = dy*inv, nz = dz*inv;
    float sh0, sh1, sh2, sh3, sh4, sh5, sh6, sh7, sh8;
    {
        const float C0 = 0.28209479177387814f;
        const float C1 = 0.4886025119029199f;
        const float C20 = 1.0925484305920792f, C21 = -1.0925484305920792f;
        const float C22 = 0.31539156525252005f;
        const float C23 = -1.0925484305920792f, C24 = 0.5462742152960396f;
        sh0 = C0;
        sh1 = -C1*ny;
        sh2 =  C1*nz;
        sh3 = -C1*nx;
        sh4 = C20*nx*ny;
        sh5 = C21*ny*nz;
        sh6 = C22*(2.0f*nz*nz - nx*nx - ny*ny);
        sh7 = C23*nx*nz;
        sh8 = C24*(nx*nx - ny*ny);
    }

    // ---- phase 1: lane-per-corner gather; wave handles 8 consecutive samples ----
    const int samp   = lane >> 3;     // 0..7
    const int corner = lane & 7;      // bit0=dx, bit1=dy, bit2=dz
    const int cdx = corner & 1, cdy = (corner >> 1) & 1, cdz = corner >> 2;

    for (int base = wave*8; base < n_proc; base += 32) {
        const int s = base + samp;
        float rr = 0.0f, gg = 0.0f, bb = 0.0f, sg = 0.0f;
        float t0 = 0.0f, dist = 0.0f;
        bool live = false;
        if (s < n_proc) {
            t0 = fminf(start + (float)(s+1)*INV127, stop);
            const float t1 = fminf(start + (float)(s+2)*INV127, stop);
            dist = (t1 - t0) * dnorm;
            live = dist > 0.0f;
        }
        if (live) {
            const float gx = (ox + t0*dx + 1.0f)*63.5f;
            const float gy = (oy + t0*dy + 1.0f)*63.5f;
            const float gz = (oz + t0*dz + 1.0f)*63.5f;
            const float fx0 = floorf(gx), fy0 = floorf(gy), fz0 = floorf(gz);
            const float fx = gx - fx0, fy = gy - fy0, fz = gz - fz0;
            const int xi = (int)fx0 + cdx;
            const int yi = (int)fy0 + cdy;
            const int zi = (int)fz0 + cdz;
            const bool valid = ((unsigned)xi < (unsigned)RESG) &
                               ((unsigned)yi < (unsigned)RESG) &
                               ((unsigned)zi < (unsigned)RESG);
            const float w = (cdx ? fx : 1.0f-fx) *
                            (cdy ? fy : 1.0f-fy) *
                            (cdz ? fz : 1.0f-fz);
            if (valid && w != 0.0f) {
                const float4* row = (const float4*)(grid + (size_t)(((zi*RESG) + yi)*RESG + xi)*CHG);
                const float4 v0 = row[0], v1 = row[1], v2 = row[2], v3 = row[3];
                const float4 v4 = row[4], v5 = row[5], v6 = row[6];
                rr = w*(v0.x*sh0 + v0.y*sh1 + v0.z*sh2 + v0.w*sh3 +
                        v1.x*sh4 + v1.y*sh5 + v1.z*sh6 + v1.w*sh7 + v2.x*sh8);
                gg = w*(v2.y*sh0 + v2.z*sh1 + v2.w*sh2 + v3.x*sh3 +
                        v3.y*sh4 + v3.z*sh5 + v3.w*sh6 + v4.x*sh7 + v4.y*sh8);
                bb = w*(v4.z*sh0 + v4.w*sh1 + v5.x*sh2 + v5.y*sh3 +
                        v5.z*sh4 + v5.w*sh5 + v6.x*sh6 + v6.y*sh7 + v6.z*sh8);
                sg = w*v6.w;
            }
        }
        // reduce over the 8 corner lanes (bits 0..2 of lane)
        #pragma unroll
        for (int off = 1; off < 8; off <<= 1) {
            rr += __shfl_xor(rr, off, 64);
            gg += __shfl_xor(gg, off, 64);
            bb += __shfl_xor(bb, off, 64);
            sg += __shfl_xor(sg, off, 64);
        }
        if (corner == 0 && s < n_proc) {
            const float a = live ? 1.0f - expf(-fmaxf(sg, 0.0f)*dist) : 0.0f;
            a_lds[s] = a;
            r_lds[s] = 1.0f/(1.0f + expf(-rr));
            g_lds[s] = 1.0f/(1.0f + expf(-gg));
            b_lds[s] = 1.0f/(1.0f + expf(-bb));
        }
    }
    __syncthreads();

    // coalesced alpha output (zeros for the dead range)
    for (int s = tid; s < NT; s += 256)
        out_alpha[(size_t)ray*NT + s] = (s < n_proc) ? a_lds[s] : 0.0f;

    // ---- phase 2: per-thread 3 consecutive samples from LDS ----
    float a_r[3], q_r[3], t_r[3], rr_r[3], gg_r[3], bb_r[3];
    #pragma unroll
    for (int k = 0; k < 3; ++k) {
        const int s = tid*3 + k;
        float a = 0.0f, rr = 0.0f, gg = 0.0f, bb = 0.0f, tt = 0.0f;
        if (s < NT) {
            tt = fminf(start + (float)(s+1)*INV127, stop);
            if (s < n_proc) {
                a  = a_lds[s];
                rr = r_lds[s]; gg = g_lds[s]; bb = b_lds[s];
            }
        }
        a_r[k] = a; q_r[k] = (s < NT) ? (1.0f - a + EPSC) : 1.0f;
        t_r[k] = tt; rr_r[k] = rr; gg_r[k] = gg; bb_r[k] = bb;
    }

    // ---- block-wide exclusive product scan ----
    const float P = q_r[0]*q_r[1]*q_r[2];
    float incl = P;
    #pragma unroll
    for (int off = 1; off < 64; off <<= 1) {
        const float n = __shfl_up(incl, off, 64);
        if (lane >= off) incl *= n;
    }
    float excl = __shfl_up(incl, 1, 64);
    if (lane == 0) excl = 1.0f;

    if (lane == 63) wprod[wave] = incl;
    __syncthreads();
    float wpre = 1.0f;
    for (int w2 = 0; w2 < 4; ++w2) if (w2 < wave) wpre *= wprod[w2];

    // ---- phase 3: weighted accumulation ----
    float cum = wpre * excl;
    float accA = 0.0f, accR = 0.0f, accG = 0.0f, accB = 0.0f, accD = 0.0f;
    #pragma unroll
    for (int k = 0; k < 3; ++k) {
        const float abs_l = a_r[k] * cum;
        accA += abs_l;
        accR += abs_l * rr_r[k];
        accG += abs_l * gg_r[k];
        accB += abs_l * bb_r[k];
        accD += abs_l * t_r[k];
        cum *= q_r[k];
    }

    #pragma unroll
    for (int off = 32; off > 0; off >>= 1) {
        accA += __shfl_down(accA, off, 64);
        accR += __shfl_down(accR, off, 64);
        accG += __shfl_down(accG, off, 64);
        accB += __shfl_down(accB, off, 64);
        accD += __shfl_down(accD, off, 64);
    }
    if (lane == 0) {
        red[wave][0] = accA; red[wave][1] = accR; red[wave][2] = accG;
        red[wave][3] = accB; red[wave][4] = accD;
    }
    __syncthreads();
    if (tid == 0) {
        float A = 0.0f, R = 0.0f, G = 0.0f, Bv = 0.0f, D = 0.0f;
        #pragma unroll
        for (int w2 = 0; w2 < 4; ++w2) {
            A += red[w2][0]; R += red[w2][1]; G += red[w2][2];
            Bv += red[w2][3]; D += red[w2][4];
        }
        const float bg = 1.0f - A;
        out_rgb[ray*3+0] = R  + bg;
        out_rgb[ray*3+1] = G  + bg;
        out_rgb[ray*3+2] = Bv + bg;
        out_depth[ray] = D;
    }
}

extern "C" void kernel_launch(void* const* d_in, const int* in_sizes, int n_in,
                              void* d_out, int out_size, void* d_ws, size_t ws_size,
                              hipStream_t stream) {
    const float* rays_d = (const float*)d_in[0];
    const float* rays_o = (const float*)d_in[1];
    const float* grid   = (const float*)d_in[2];
    const int B = in_sizes[0] / 3;   // 4096

    float* out       = (float*)d_out;
    float* out_rgb   = out;                                  // B*3
    float* out_alpha = out + (size_t)B*3;                    // B*767
    float* out_depth = out + (size_t)B*3 + (size_t)B*NT;     // B

    nerf_grid_kernel<<<B, 256, 0, stream>>>(rays_d, rays_o, grid,
                                            out_rgb, out_alpha, out_depth);
}